// Round 14
// baseline (269.102 us; speedup 1.0000x reference)
//
#include <hip/hip_runtime.h>
#include <hip/hip_bf16.h>

#define N_NODES 50000
#define N_EDGES 800000
#define IN_CH 64
#define HID_CH 128
#define OUT_CH 64
#define N_GRAPHS 512
#define CAP 64         // padded CSR capacity per node (Poisson(16): P(deg>64) ~ e^-42)
#define TN 16          // nodes per stage in node_kernel (50000 % 16 == 0)
#define NPB 64         // nodes per block: 782 blocks ~ 3/CU for gather/GEMV overlap
#define NSTAGE (NPB / TN)

typedef unsigned short ushort_t;
typedef unsigned int uint_t;

__device__ __forceinline__ void atomAddF(float* p, float v) {
    unsafeAtomicAdd(p, v);  // HW global_atomic_add_f32 on gfx950
}

__device__ __forceinline__ ushort_t f2bf(float f) {   // RNE f32->bf16
    uint_t b = __float_as_uint(f);
    return (ushort_t)((b + 0x7fffu + ((b >> 16) & 1u)) >> 16);
}

// K1: x -> bf16 table; ALSO zeroes degi/pooled/counts (replaces the memset
// graph node: each graph dispatch costs ~18-20 us of gap, r1/r9/r13 deltas).
__global__ __launch_bounds__(256) void convert_x(
    const float* __restrict__ x, ushort_t* __restrict__ xh,
    int* __restrict__ degi, float* __restrict__ pooled,
    float* __restrict__ counts)
{
    int i = blockIdx.x * 256 + threadIdx.x;          // float8 index
    if (i < N_NODES) degi[i] = 0;
    if (i < N_GRAPHS * HID_CH) pooled[i] = 0.f;
    if (i < N_GRAPHS) counts[i] = 0.f;
    if (i >= N_NODES * IN_CH / 8) return;
    const float4 f0 = *reinterpret_cast<const float4*>(x + (size_t)i * 8);
    const float4 f1 = *reinterpret_cast<const float4*>(x + (size_t)i * 8 + 4);
    uint4 o;
    o.x = (uint_t)f2bf(f0.x) | ((uint_t)f2bf(f0.y) << 16);
    o.y = (uint_t)f2bf(f0.z) | ((uint_t)f2bf(f0.w) << 16);
    o.z = (uint_t)f2bf(f1.x) | ((uint_t)f2bf(f1.y) << 16);
    o.w = (uint_t)f2bf(f1.z) | ((uint_t)f2bf(f1.w) << 16);
    *reinterpret_cast<uint4*>(xh + (size_t)i * 8) = o;
}

// K2: one pass over edges; degi counts, csr16 gets src ids (u16: src < 65536).
__global__ __launch_bounds__(256) void scatter_pad(
    const int* __restrict__ ei, int* __restrict__ degi,
    ushort_t* __restrict__ csr16)
{
    int e = blockIdx.x * 256 + threadIdx.x;
    if (e >= N_EDGES) return;
    int src = ei[e];
    int dst = ei[N_EDGES + e];
    int pos = atomicAdd(&degi[dst], 1);
    csr16[(dst << 6) + pos] = (ushort_t)src;
}

// K3: FUSED gather + node phase. Per 16-node stage: all 256 threads stage the
// x-half of feat; each of the 4 waves gathers 4 nodes' neighbor MEANS from
// the bf16 table directly into the agg-half of feat (no global agg buffer);
// then the proven v5 GEMV/attention/pool phases run unchanged. Gather latency
// of one resident block overlaps GEMV VALU of the others (~3 blocks/CU).
__global__ __launch_bounds__(256, 4) void node_kernel(
    const float* __restrict__ x, const ushort_t* __restrict__ xh,
    const ushort_t* __restrict__ csr16, const int* __restrict__ degi,
    const int* __restrict__ batch,
    const float* __restrict__ Wl, const float* __restrict__ bl,
    const float* __restrict__ Wr, const float* __restrict__ Watt,
    const float* __restrict__ batt,
    float* __restrict__ pooled, float* __restrict__ counts)
{
    const int t    = threadIdx.x;
    const int jp   = t & 63;    // channel pair: j0=jp, j1=jp+64
    const int q    = t >> 6;    // input-channel quarter (= wave id)
    const int lane = t & 63;
    const int g8   = lane >> 3; // gather: neighbor group 0..7
    const int c8   = lane & 7;  // gather: channel octet

    float4 wl0[4], wl1[4], wr0[4], wr1[4];   // 64 weight floats/thread
#pragma unroll
    for (int c = 0; c < 4; ++c) {
        wl0[c] = *reinterpret_cast<const float4*>(Wl + (size_t)jp * IN_CH + q * 16 + c * 4);
        wr0[c] = *reinterpret_cast<const float4*>(Wr + (size_t)jp * IN_CH + q * 16 + c * 4);
        wl1[c] = *reinterpret_cast<const float4*>(Wl + (size_t)(jp + 64) * IN_CH + q * 16 + c * 4);
        wr1[c] = *reinterpret_cast<const float4*>(Wr + (size_t)(jp + 64) * IN_CH + q * 16 + c * 4);
    }
    const int jj    = t & 127;          // channel for phases 2-3 (t<128)
    const float blj = bl[jj];
    const float wa  = Watt[jj];
    const float ba  = batt[0];

    __shared__ __align__(16) float4 feat[TN][32];   // [node][0-15:x, 16-31:agg]
    float* sh = reinterpret_cast<float*>(feat);     // aliased: h[TN][128] post-GEMV
    __shared__ float psum[4][TN][HID_CH];           // [quarter][node][channel]
    __shared__ float sred[2][TN];
    __shared__ float ss[TN];

    float accp = 0.f, cnt = 0.f;
    const int nb0 = blockIdx.x * NPB;
    int curb = batch[nb0];

    for (int s = 0; s < NSTAGE; ++s) {
        const int nb = nb0 + s * TN;
        if (nb >= N_NODES) break;   // tail block: fewer full stages
        __syncthreads();            // prev stage readers done (feat/sh/ss)

        // (A) stage x-half: thread t -> node t>>4, slot t&15 (coalesced 256B/row)
        {
            int node = t >> 4, slot = t & 15;
            feat[node][slot] = *reinterpret_cast<const float4*>(
                x + (size_t)(nb + node) * IN_CH + slot * 4);
        }
        // (B) gather agg-half: wave q handles stage nodes 4q..4q+3
#pragma unroll
        for (int u = 0; u < 4; ++u) {
            const int n    = (q << 2) | u;
            const int node = nb + n;
            const int d    = degi[node];
            const ushort_t* b = csr16 + ((size_t)node << 6);
            float a0[8] = {0.f,0.f,0.f,0.f,0.f,0.f,0.f,0.f};
            float a1[8] = {0.f,0.f,0.f,0.f,0.f,0.f,0.f,0.f};
            int i = g8;
            for (; i + 8 < d; i += 16) {    // 2 rows in flight per group
                int s0 = b[i], s1 = b[i + 8];
                uint4 u0 = *reinterpret_cast<const uint4*>(xh + (size_t)s0 * IN_CH + c8 * 8);
                uint4 u1 = *reinterpret_cast<const uint4*>(xh + (size_t)s1 * IN_CH + c8 * 8);
                a0[0] += __uint_as_float(u0.x << 16); a0[1] += __uint_as_float(u0.x & 0xffff0000u);
                a0[2] += __uint_as_float(u0.y << 16); a0[3] += __uint_as_float(u0.y & 0xffff0000u);
                a0[4] += __uint_as_float(u0.z << 16); a0[5] += __uint_as_float(u0.z & 0xffff0000u);
                a0[6] += __uint_as_float(u0.w << 16); a0[7] += __uint_as_float(u0.w & 0xffff0000u);
                a1[0] += __uint_as_float(u1.x << 16); a1[1] += __uint_as_float(u1.x & 0xffff0000u);
                a1[2] += __uint_as_float(u1.y << 16); a1[3] += __uint_as_float(u1.y & 0xffff0000u);
                a1[4] += __uint_as_float(u1.z << 16); a1[5] += __uint_as_float(u1.z & 0xffff0000u);
                a1[6] += __uint_as_float(u1.w << 16); a1[7] += __uint_as_float(u1.w & 0xffff0000u);
            }
            if (i < d) {
                int s0 = b[i];
                uint4 u0 = *reinterpret_cast<const uint4*>(xh + (size_t)s0 * IN_CH + c8 * 8);
                a0[0] += __uint_as_float(u0.x << 16); a0[1] += __uint_as_float(u0.x & 0xffff0000u);
                a0[2] += __uint_as_float(u0.y << 16); a0[3] += __uint_as_float(u0.y & 0xffff0000u);
                a0[4] += __uint_as_float(u0.z << 16); a0[5] += __uint_as_float(u0.z & 0xffff0000u);
                a0[6] += __uint_as_float(u0.w << 16); a0[7] += __uint_as_float(u0.w & 0xffff0000u);
            }
#pragma unroll
            for (int k = 0; k < 8; ++k) {
                a0[k] += a1[k];
                a0[k] += __shfl_xor(a0[k], 8);
                a0[k] += __shfl_xor(a0[k], 16);
                a0[k] += __shfl_xor(a0[k], 32);
            }
            if (g8 == 0) {
                float inv = 1.0f / fmaxf((float)d, 1.0f);
                feat[n][16 + 2 * c8] = make_float4(a0[0] * inv, a0[1] * inv,
                                                   a0[2] * inv, a0[3] * inv);
                feat[n][17 + 2 * c8] = make_float4(a0[4] * inv, a0[5] * inv,
                                                   a0[6] * inv, a0[7] * inv);
            }
        }
        __syncthreads();

        // GEMV quarter: psum[q][n][j{0,1}] over this thread's 16 input chans
#pragma unroll
        for (int n = 0; n < TN; ++n) {
            float p0a = 0.f, p0b = 0.f, p1a = 0.f, p1b = 0.f;
#pragma unroll
            for (int c = 0; c < 4; ++c) {
                float4 xv = feat[n][q * 4 + c];        // wave-broadcast
                float4 av = feat[n][16 + q * 4 + c];
                p0a += wr0[c].x * xv.x + wr0[c].y * xv.y
                     + wl0[c].x * av.x + wl0[c].y * av.y;
                p0b += wr0[c].z * xv.z + wr0[c].w * xv.w
                     + wl0[c].z * av.z + wl0[c].w * av.w;
                p1a += wr1[c].x * xv.x + wr1[c].y * xv.y
                     + wl1[c].x * av.x + wl1[c].y * av.y;
                p1b += wr1[c].z * xv.z + wr1[c].w * xv.w
                     + wl1[c].z * av.z + wl1[c].w * av.w;
            }
            psum[q][n][jp]      = p0a + p0b;
            psum[q][n][jp + 64] = p1a + p1b;
        }
        __syncthreads();

        // phase 2: h = relu(sum_q psum + bl); cache h in sh; attention partial
        if (t < 128) {
#pragma unroll
            for (int n = 0; n < TN; ++n) {
                float h = psum[0][n][jj] + psum[1][n][jj]
                        + psum[2][n][jj] + psum[3][n][jj] + blj;
                h = fmaxf(h, 0.f);
                sh[n * HID_CH + jj] = h;
                float r = wa * h;
                r += __shfl_xor(r, 1);  r += __shfl_xor(r, 2);
                r += __shfl_xor(r, 4);  r += __shfl_xor(r, 8);
                r += __shfl_xor(r, 16); r += __shfl_xor(r, 32);
                if (lane == n) sred[t >> 6][n] = r;
            }
        }
        __syncthreads();
        if (t < TN) ss[t] = 1.f / (1.f + expf(-(sred[0][t] + sred[1][t] + ba)));
        __syncthreads();

        // phase 3: pooled accumulation with batch flush (t<128)
        if (t < 128) {
#pragma unroll
            for (int n = 0; n < TN; ++n) {
                float hs = sh[n * HID_CH + jj] * ss[n];
                int b = batch[nb + n];
                if (b != curb) {
                    atomAddF(&pooled[(size_t)curb * HID_CH + jj], accp);
                    if (jj == 0) atomAddF(&counts[curb], cnt);
                    accp = 0.f; cnt = 0.f; curb = b;
                }
                accp += hs;
                cnt  += 1.f;
            }
        }
    }
    if (t < 128) {
        atomAddF(&pooled[(size_t)curb * HID_CH + jj], accp);
        if (jj == 0) atomAddF(&counts[curb], cnt);
    }
}

// K4: out[g][j] = bout[j] + sum_c Wout[j][c] * pooled_mean[g][c]
__global__ __launch_bounds__(64) void out_kernel(
    const float* __restrict__ pooled, const float* __restrict__ counts,
    const float* __restrict__ Wout, const float* __restrict__ bout,
    float* __restrict__ out)
{
    const int g = blockIdx.x;
    const int j = threadIdx.x;
    __shared__ __align__(16) float sp[HID_CH];
    float inv = 1.0f / fmaxf(counts[g], 1.0f);
    sp[j]      = pooled[(size_t)g * HID_CH + j] * inv;
    sp[j + 64] = pooled[(size_t)g * HID_CH + 64 + j] * inv;
    __syncthreads();
    float acc = bout[j];
#pragma unroll
    for (int c4 = 0; c4 < HID_CH / 4; ++c4) {
        float4 w = *reinterpret_cast<const float4*>(Wout + (size_t)j * HID_CH + c4 * 4);
        acc += w.x * sp[c4 * 4 + 0] + w.y * sp[c4 * 4 + 1]
             + w.z * sp[c4 * 4 + 2] + w.w * sp[c4 * 4 + 3];
    }
    out[(size_t)g * OUT_CH + j] = acc;
}

extern "C" void kernel_launch(void* const* d_in, const int* in_sizes, int n_in,
                              void* d_out, int out_size, void* d_ws, size_t ws_size,
                              hipStream_t stream)
{
    const float* x     = (const float*)d_in[0];
    const int*   ei    = (const int*)d_in[1];
    const int*   batch = (const int*)d_in[2];
    const float* Wl    = (const float*)d_in[3];
    const float* bl    = (const float*)d_in[4];
    const float* Wr    = (const float*)d_in[5];
    const float* Watt  = (const float*)d_in[6];
    const float* batt  = (const float*)d_in[7];
    const float* Wout  = (const float*)d_in[8];
    const float* bout  = (const float*)d_in[9];
    float* out = (float*)d_out;

    // workspace layout (no memset: convert_x zeroes degi/pooled/counts)
    int*      degi   = (int*)d_ws;
    float*    pooled = (float*)(degi + N_NODES);
    float*    counts = pooled + (size_t)N_GRAPHS * HID_CH;
    ushort_t* csr16  = (ushort_t*)(counts + N_GRAPHS);            // written by scatter
    ushort_t* xh     = csr16 + (size_t)N_NODES * CAP;             // written by convert

    convert_x<<<(N_NODES * IN_CH / 8 + 255) / 256, 256, 0, stream>>>(
        x, xh, degi, pooled, counts);
    scatter_pad<<<(N_EDGES + 255) / 256, 256, 0, stream>>>(ei, degi, csr16);
    node_kernel<<<(N_NODES + NPB - 1) / NPB, 256, 0, stream>>>(
        x, xh, csr16, degi, batch, Wl, bl, Wr, Watt, batt, pooled, counts);
    out_kernel<<<N_GRAPHS, 64, 0, stream>>>(pooled, counts, Wout, bout, out);
}